// Round 17
// baseline (58.246 us; speedup 1.0000x reference)
//
#include <hip/hip_runtime.h>
#include <stdint.h>

typedef __bf16 bf16x8 __attribute__((ext_vector_type(8)));
typedef float  f32x4  __attribute__((ext_vector_type(4)));

#define B_TOT 16384
#define GS    4           // batches (waves) per k_tok block
#define MB2   32          // batches per k_mlp block

// ws layout (byte offsets)
#define OFF_W1T   0u          // [550][128] bf16
#define OFF_W2B   141312u     // [128][1152] bf16 (w2b[oc][pos*128+ic])
#define OFF_FCB   436224u     // [256][128] bf16
#define OFF_WH    501760u     // [32][512] bf16 (head weights, N padded to 32)
#define OFF_BH    534528u     // [32] f32 head bias
#define OFF_SWB   534656u     // [256][32] bf16 self_w padded K 22->32
#define OFF_SELFV 551040u     // [16384][32] bf16 center-cell features
#define OFF_PCG   1599616u    // [16384][9] u32 bucket counts
#define OFF_ENT   2189440u    // [16384][9][12] u32 bucket entries (~7.1MB)

__device__ const float d_maxv[22] = {
  9.f,1.f,1.f,10.f,3.f,254.f,1.f,1.f,235.f,8.f,
  9.f,250.f,29.f,1.f,1.f,8.f,1.f,1.f,6.f,3.f,1.f,2.f };

static __device__ __forceinline__ short f2bf(float f){
  union { float f; uint32_t u; } c; c.f = f;
  uint32_t r = (c.u + 0x7FFFu + ((c.u >> 16) & 1u)) >> 16;  // RNE
  return (short)r;
}
static __device__ __forceinline__ float bf2f(short s){
  union { uint32_t u; float f; } c; c.u = ((uint32_t)(uint16_t)s) << 16;
  return c.f;
}
// packed RNE f32x2 -> bf16x2 (single HW instruction)
static __device__ __forceinline__ uint32_t cvtpk(float lo, float hi){
  uint32_t pk;
  asm("v_cvt_pk_bf16_f32 %0, %1, %2" : "=v"(pk) : "v"(lo), "v"(hi));
  return pk;
}
// XOR-swizzled short index for [row][k] LDS tiles (stride: shorts, mult of 64)
static __device__ __forceinline__ int swz(int row, int k, int stride){
  return row * stride + ((((k >> 3) ^ (row & 7)) << 3) | (k & 7));
}
// async global->LDS, 16B per lane; lds dest = wave-uniform base + lane*16
static __device__ __forceinline__ void gld16(const void* g, void* l){
  __builtin_amdgcn_global_load_lds(
      (const __attribute__((address_space(1))) void*)g,
      (__attribute__((address_space(3))) void*)l, 16, 0, 0);
}
static __device__ __forceinline__ void wavesync(){
  asm volatile("s_waitcnt lgkmcnt(0)" ::: "memory");
  __builtin_amdgcn_wave_barrier();
}

// ---------------- prep: repack weights to bf16 GEMM layouts ----------------
__global__ __launch_bounds__(256) void k_prep(
    const float* __restrict__ c1w, const float* __restrict__ c2w,
    const float* __restrict__ fcw, const float* __restrict__ a0w,
    const float* __restrict__ a1w, const float* __restrict__ vw,
    const float* __restrict__ a0b, const float* __restrict__ a1b,
    const float* __restrict__ vb,  const float* __restrict__ selfw,
    short* __restrict__ w1t, short* __restrict__ w2b, short* __restrict__ fcb,
    short* __restrict__ wh, float* __restrict__ bh, short* __restrict__ swB)
{
  int i = blockIdx.x * 256 + threadIdx.x;
  if (i < 70400) {                    // w1t[r*128+oc] = c1w[oc*550 + r]
    int r = i >> 7, oc = i & 127;
    w1t[i] = f2bf(c1w[oc * 550 + r]);
  }
  i -= 70400;
  if (i >= 0 && i < 147456) {         // w2b[oc*1152 + pos*128+ic]
    int oc = i / 1152, k = i - oc * 1152;
    int pos = k >> 7, ic = k & 127;
    w2b[i] = f2bf(c2w[oc * 1152 + ic * 9 + pos]);
  }
  i -= 147456;
  if (i >= 0 && i < 32768) fcb[i] = f2bf(fcw[i]);   // fc_w already [n][k]
  i -= 32768;
  if (i >= 0 && i < 16384) {          // wh[j*512+k], j in [0,32)
    int j = i >> 9, k = i & 511;
    float v = 0.f;
    if (j < 9) v = a0w[j * 512 + k];
    else if (j < 19) v = a1w[(j - 9) * 512 + k];
    else if (j == 19) v = vw[k];
    wh[i] = f2bf(v);
  }
  i -= 16384;
  if (i >= 0 && i < 32) {
    float v = 0.f;
    if (i < 9) v = a0b[i]; else if (i < 19) v = a1b[i - 9]; else if (i == 19) v = vb[0];
    bh[i] = v;
  }
  i -= 32;
  if (i >= 0 && i < 8192) {           // swB[o*32+l] = selfw[o*22+l], K-pad 0
    int o = i >> 5, l = i & 31;
    swB[i] = (l < 22) ? f2bf(selfw[o * 22 + l]) : (short)0;
  }
}

// ---- tokenizer: parse + dedup + per-position buckets + selfv. 1 wave/batch ----
// bucket entry = (r<<13)|(l<<8)|v8  (r<550: 10b, l<22: 5b)
__global__ __launch_bounds__(256) void k_tok(
    const int* __restrict__ obs,
    short* __restrict__ selfvB, uint32_t* __restrict__ entG,
    uint32_t* __restrict__ pcntG)
{
  __shared__ uint32_t nzl[GS * 64];
  __shared__ uint32_t bkt[GS * 108];     // [4 batches][9 pos][12 slots]
  __shared__ uint32_t cnt[GS];
  __shared__ uint32_t pcnt[GS * 9];
  __shared__ float selfv[GS * 24];
  __shared__ float invS[22];

  const int tid = threadIdx.x, wid = tid >> 6, lane = tid & 63;
  const int b = blockIdx.x * GS + wid;

  if (lane == 0) cnt[wid] = 0u;
  if (lane < 9)  pcnt[wid * 9 + lane] = 0u;
  if (lane < 24) selfv[wid * 24 + lane] = 0.f;
  for (int i = lane; i < 108; i += 64) bkt[wid * 108 + i] = 0u;  // determinism
  if (tid < 22) invS[tid] = 1.0f / (d_maxv[tid] + 1e-8f);
  __syncthreads();                       // invS

  // ---- parse: wave-private batch, direct from global ----
  {
    const int* base = obs + (size_t)b * 600;
    #pragma unroll
    for (int k = 0; k < 4; ++k) {
      int m = lane + (k << 6);
      if (m < 200) {
        int c = base[m * 3], a = base[m * 3 + 1], v = base[m * 3 + 2];
        c = (c == 255) ? 0 : c;  a = (a == 255) ? 0 : a;  v = (v == 255) ? 0 : v;
        int x = (c >> 4) & 15, y = c & 15;
        if (x < 11 && y < 11 && a < 22) {
          uint32_t cell = (uint32_t)(a * 121 + x * 11 + y);
          uint32_t idx = atomicAdd(&cnt[wid], 1u);
          if (idx < 64u)
            nzl[wid * 64 + idx] = ((uint32_t)m << 20) | (cell << 8) | (uint32_t)v;
        }
      }
    }
  }
  wavesync();

  // ---- dedup (last-write-wins = max pack per cell) + bucket expand + selfv ----
  {
    uint32_t n = cnt[wid]; if (n > 64u) n = 64u;
    for (uint32_t i = lane; i < n; i += 64) {
      uint32_t e = nzl[wid * 64 + i];
      uint32_t cell = (e >> 8) & 0xFFFu;
      uint32_t best = e;
      for (uint32_t j = 0; j < n; ++j) {
        uint32_t ej = nzl[wid * 64 + j];
        if ((((ej >> 8) & 0xFFFu) == cell) && ej > best) best = ej;
      }
      if (best == e && (e & 255u) != 0u) {
        uint32_t v8 = e & 255u;
        uint32_t l = cell / 121u, rem = cell - l * 121u;
        uint32_t x = rem / 11u, y = rem - x * 11u;
        if (rem == 60u)                            // x=5,y=5 center
          selfv[wid * 24 + l] = (float)v8 * invS[l];
        #pragma unroll
        for (int ox = 0; ox < 3; ++ox) {
          int kx = (int)x - 3 * ox; if (kx < 0 || kx > 4) continue;
          #pragma unroll
          for (int oy = 0; oy < 3; ++oy) {
            int ky = (int)y - 3 * oy; if (ky < 0 || ky > 4) continue;
            uint32_t r = l * 25u + (uint32_t)kx * 5u + (uint32_t)ky;
            uint32_t p = (uint32_t)(ox * 3 + oy);
            uint32_t s = atomicAdd(&pcnt[wid * 9 + p], 1u);
            if (s < 12u)
              bkt[wid * 108 + p * 12 + s] = (r << 13) | (l << 8) | v8;
          }
        }
      }
    }
  }
  wavesync();

  // selfvB [b][32] bf16 (K-padded)
  if (lane < 16) {
    int l0 = lane * 2;
    float v0 = (l0     < 22) ? selfv[wid * 24 + l0]     : 0.f;
    float v1 = (l0 + 1 < 22) ? selfv[wid * 24 + l0 + 1] : 0.f;
    *(uint32_t*)(selfvB + (size_t)b * 32 + l0) = cvtpk(v0, v1);
  }
  // write buckets + counts
  for (int i = lane; i < 108; i += 64) entG[(size_t)b * 108 + i] = bkt[wid * 108 + i];
  if (lane < 9) {
    uint32_t m = pcnt[wid * 9 + lane];
    pcntG[(size_t)b * 9 + lane] = (m > 12u) ? 12u : m;
  }
}

// -- fused conv1(per-position LDS A-tile) -> conv2 -> fc -> self -> heads --
// 32 batches/block, 512 threads, 56KB LDS -> 2 blocks/CU.
__global__ __launch_bounds__(512, 4) void k_mlp(
    const uint32_t* __restrict__ entG, const uint32_t* __restrict__ pcntG,
    const short* __restrict__ selfvB, const short* __restrict__ w1t,
    const short* __restrict__ w2b, const short* __restrict__ fcb,
    const short* __restrict__ wh,  const short* __restrict__ swB,
    const float* __restrict__ c1b, const float* __restrict__ c2b,
    const float* __restrict__ fcbias, const float* __restrict__ selfb,
    const float* __restrict__ bh, float* __restrict__ out)
{
  // shorts: Bbuf0 [0,8192) | Bbuf1 [8192,16384) | Atile [16384,20480)
  //         tokS u32 [20480,27392) | pcntS u32 [27392,27968) | invS [27968,28012)
  // post-conv2 aliases: h2s [0,4096) s128 | cfs [4096,12288) s256 |
  //                     sfl [12288,20480) s256 | hacc f32[2][1024] on [0,4096)
  __shared__ __align__(16) short smem[28032];
  uint32_t* tokS  = (uint32_t*)(smem + 20480);
  uint32_t* pcntS = (uint32_t*)(smem + 27392);
  float*    invL  = (float*)(smem + 27968);
  short*    Atile = smem + 16384;

  const int tid  = threadIdx.x, wid = tid >> 6, lane = tid & 63;
  const int l15 = lane & 15, kg = lane >> 4;
  const int wr = wid & 1, wc = wid >> 1;
  const int rowA = wr * 16 + l15;
  const size_t b0 = (size_t)blockIdx.x * MB2;
  const f32x4 z4 = {0.f, 0.f, 0.f, 0.f};

  // conv1 mapping: thread = (batch, ic-group of 8)
  const int cb1 = tid >> 4;           // batch 0..31
  const int icg = tid & 15;
  const int ic0 = icg * 8;

  // ---- stage tokS + pcntS + invS ----
  {
    const int4* src = (const int4*)(entG + b0 * 108);
    int4* dst = (int4*)tokS;
    for (int i = tid; i < 864; i += 512) dst[i] = src[i];
  }
  if (tid < 288) pcntS[tid] = pcntG[b0 * 9 + tid];
  if (tid < 22) invL[tid] = 1.0f / (d_maxv[tid] + 1e-8f);

  // conv1 bias in registers
  float bz[8];
  #pragma unroll
  for (int j = 0; j < 8; ++j) bz[j] = c1b[ic0 + j];

  // ---- B staging: 16 chunks/tile, wave w issues 2 ----
  const int sub = lane >> 3, pch = lane & 7;
  const int ocj0 = (wid * 2) * 8 + sub, ocj1 = (wid * 2 + 1) * 8 + sub;
  const short* gB0 = w2b + (size_t)ocj0 * 1152 + ((pch ^ (ocj0 & 7)) << 3);
  const short* gB1 = w2b + (size_t)ocj1 * 1152 + ((pch ^ (ocj1 & 7)) << 3);
  const int dB0 = (wid * 2) * 512, dB1 = (wid * 2 + 1) * 512;

  gld16(gB0, &smem[dB0]); gld16(gB1, &smem[dB1]);   // B(0) -> buf0
  __syncthreads();                                  // tokS visible (drains B(0) too)

  f32x4 acc[2] = {z4, z4};
  for (int t = 0; t < 18; ++t) {
    if ((t & 1) == 0) {
      // ---- produce A(p): conv1 for position p into Atile ----
      const int p = t >> 1;
      float a8[8];
      #pragma unroll
      for (int j = 0; j < 8; ++j) a8[j] = bz[j];
      const int n = (int)pcntS[cb1 * 9 + p];
      for (int i = 0; i < n; ++i) {
        uint32_t e = tokS[cb1 * 108 + p * 12 + i];
        int r = (int)(e >> 13);
        float vf = (float)(e & 255u) * invL[(e >> 8) & 31u];
        const uint32_t* wp = (const uint32_t*)(const void*)&w1t[r * 128 + ic0];
        uint32_t w0 = wp[0], w1 = wp[1], w2 = wp[2], w3 = wp[3];
        a8[0] += vf * bf2f((short)(w0 & 0xFFFFu));
        a8[1] += vf * bf2f((short)(w0 >> 16));
        a8[2] += vf * bf2f((short)(w1 & 0xFFFFu));
        a8[3] += vf * bf2f((short)(w1 >> 16));
        a8[4] += vf * bf2f((short)(w2 & 0xFFFFu));
        a8[5] += vf * bf2f((short)(w2 >> 16));
        a8[6] += vf * bf2f((short)(w3 & 0xFFFFu));
        a8[7] += vf * bf2f((short)(w3 >> 16));
      }
      uint32_t* ad = (uint32_t*)(void*)&Atile[swz(cb1, ic0, 128)];
      ad[0] = cvtpk(fmaxf(a8[0], 0.f), fmaxf(a8[1], 0.f));
      ad[1] = cvtpk(fmaxf(a8[2], 0.f), fmaxf(a8[3], 0.f));
      ad[2] = cvtpk(fmaxf(a8[4], 0.f), fmaxf(a8[5], 0.f));
      ad[3] = cvtpk(fmaxf(a8[6], 0.f), fmaxf(a8[7], 0.f));
    }
    const int cbB = (t & 1) * 8192;
    if (t < 17) {
      const int nbB = 8192 - cbB;
      const int ko = (t + 1) * 64;
      gld16(gB0 + ko, &smem[nbB + dB0]);
      gld16(gB1 + ko, &smem[nbB + dB1]);
      asm volatile("s_waitcnt vmcnt(2) lgkmcnt(0)" ::: "memory");
    } else {
      asm volatile("s_waitcnt vmcnt(0) lgkmcnt(0)" ::: "memory");
    }
    __builtin_amdgcn_sched_barrier(0);
    __builtin_amdgcn_s_barrier();       // B(t) staged + A(p) produced, all waves
    __builtin_amdgcn_sched_barrier(0);
    #pragma unroll
    for (int ks = 0; ks < 2; ++ks) {
      int kq = ks * 4 + kg;
      int icA = (t & 1) * 64 + kq * 8;
      bf16x8 a = *(const bf16x8*)(const void*)&Atile[swz(rowA, icA, 128)];
      #pragma unroll
      for (int nf = 0; nf < 2; ++nf) {
        int oc = wc * 32 + nf * 16 + l15;
        bf16x8 bv = *(const bf16x8*)(const void*)
                    &smem[cbB + oc * 64 + ((kq ^ (oc & 7)) << 3)];
        acc[nf] = __builtin_amdgcn_mfma_f32_16x16x32_bf16(a, bv, acc[nf], 0, 0, 0);
      }
    }
    __builtin_amdgcn_sched_barrier(0);
    __builtin_amdgcn_s_barrier();       // reads of buf + Atile done
  }
  // ---- conv2 epilogue: bias+relu -> h2s [0,4096), stride 128 ----
  #pragma unroll
  for (int nf = 0; nf < 2; ++nf) {
    int col = wc * 32 + nf * 16 + l15;
    float bias = c2b[col];
    #pragma unroll
    for (int rr = 0; rr < 4; ++rr) {      // C/D: col=lane&15, row=(lane>>4)*4+rr
      int row = wr * 16 + kg * 4 + rr;
      smem[swz(row, col, 128)] = f2bf(fmaxf(acc[nf][rr] + bias, 0.f));
    }
  }
  __syncthreads();

  // ---- fc GEMM: M=32 N=256 K=128; A from h2s, B from L2 -> cfs ----
  {
    f32x4 fca[4] = {z4, z4, z4, z4};
    #pragma unroll
    for (int kk = 0; kk < 4; ++kk) {
      int k = kk * 32 + kg * 8;
      bf16x8 a = *(const bf16x8*)(const void*)&smem[swz(rowA, k, 128)];
      #pragma unroll
      for (int nf = 0; nf < 4; ++nf) {
        int col = wc * 64 + nf * 16 + l15;
        bf16x8 bv = *(const bf16x8*)(const void*)(fcb + (size_t)col * 128 + k);
        fca[nf] = __builtin_amdgcn_mfma_f32_16x16x32_bf16(a, bv, fca[nf], 0, 0, 0);
      }
    }
    #pragma unroll
    for (int nf = 0; nf < 4; ++nf) {
      int col = wc * 64 + nf * 16 + l15;
      float bias = fcbias[col];
      #pragma unroll
      for (int rr = 0; rr < 4; ++rr) {
        int row = wr * 16 + kg * 4 + rr;
        smem[4096 + swz(row, col, 256)] = f2bf(fmaxf(fca[nf][rr] + bias, 0.f));
      }
    }
  }
  // ---- self encoder GEMM: M=32 N=256 K=32 -> sfl ----
  {
    f32x4 sa[4] = {z4, z4, z4, z4};
    bf16x8 a = *(const bf16x8*)(const void*)
               (selfvB + (b0 + (size_t)rowA) * 32 + kg * 8);
    #pragma unroll
    for (int nf = 0; nf < 4; ++nf) {
      int col = wc * 64 + nf * 16 + l15;
      bf16x8 bv = *(const bf16x8*)(const void*)(swB + (size_t)col * 32 + kg * 8);
      sa[nf] = __builtin_amdgcn_mfma_f32_16x16x32_bf16(a, bv, sa[nf], 0, 0, 0);
    }
    #pragma unroll
    for (int nf = 0; nf < 4; ++nf) {
      int col = wc * 64 + nf * 16 + l15;
      float bias = selfb[col];
      #pragma unroll
      for (int rr = 0; rr < 4; ++rr) {
        int row = wr * 16 + kg * 4 + rr;
        smem[12288 + swz(row, col, 256)] = f2bf(fmaxf(sa[nf][rr] + bias, 0.f));
      }
    }
  }
  __syncthreads();

  // ---- heads: M=32 N=32 K=512; waves = wr(2) x kh(2) x nh(2) ----
  {
    float* hacc = (float*)smem;           // [2][1024] f32, aliases h2s (dead)
    const int kh = (wid >> 1) & 1, nh = wid >> 2;
    const int ncol = nh * 16 + l15;
    f32x4 ha = z4;
    #pragma unroll
    for (int kk = 0; kk < 8; ++kk) {
      int kl = kk * 32 + kg * 8;
      bf16x8 a;
      if (kh == 0) a = *(const bf16x8*)(const void*)&smem[12288 + swz(rowA, kl, 256)];
      else         a = *(const bf16x8*)(const void*)&smem[4096  + swz(rowA, kl, 256)];
      bf16x8 bv = *(const bf16x8*)(const void*)(wh + (size_t)ncol * 512 + kh * 256 + kl);
      ha = __builtin_amdgcn_mfma_f32_16x16x32_bf16(a, bv, ha, 0, 0, 0);
    }
    #pragma unroll
    for (int rr = 0; rr < 4; ++rr) {
      int row = wr * 16 + kg * 4 + rr;
      hacc[kh * 1024 + row * 32 + ncol] = ha[rr];
    }
  }
  __syncthreads();

  // ---- reduce K-halves + bias + scatter ----
  {
    const float* hacc = (const float*)smem;
    #pragma unroll
    for (int q = 0; q < 2; ++q) {
      int i = q * 512 + tid;
      int row = i >> 5, colh = i & 31;
      float v = hacc[i] + hacc[1024 + i] + bh[colh];
      int gr = (int)b0 + row;
      if (colh < 9)        out[gr * 9 + colh] = v;                    // a0 [B][9]
      else if (colh < 19)  out[147456 + gr * 10 + (colh - 9)] = v;    // a1 [B][10]
      else if (colh == 19) out[311296 + gr] = v;                      // v  [B][1]
    }
  }
}

extern "C" void kernel_launch(void* const* d_in, const int* in_sizes, int n_in,
                              void* d_out, int out_size, void* d_ws, size_t ws_size,
                              hipStream_t stream)
{
  const int*   obs = (const int*)  d_in[0];
  const float* c1w = (const float*)d_in[1];
  const float* c1b = (const float*)d_in[2];
  const float* c2w = (const float*)d_in[3];
  const float* c2b = (const float*)d_in[4];
  const float* fcw = (const float*)d_in[5];
  const float* fcbv= (const float*)d_in[6];
  const float* sw  = (const float*)d_in[7];
  const float* sb  = (const float*)d_in[8];
  const float* a0w = (const float*)d_in[9];
  const float* a0b = (const float*)d_in[10];
  const float* a1w = (const float*)d_in[11];
  const float* a1b = (const float*)d_in[12];
  const float* vw  = (const float*)d_in[13];
  const float* vb  = (const float*)d_in[14];

  char* ws = (char*)d_ws;
  short* w1t    = (short*)(ws + OFF_W1T);
  short* w2b    = (short*)(ws + OFF_W2B);
  short* fcb    = (short*)(ws + OFF_FCB);
  short* wh     = (short*)(ws + OFF_WH);
  float* bh     = (float*)(ws + OFF_BH);
  short* swB    = (short*)(ws + OFF_SWB);
  short* selfvB = (short*)(ws + OFF_SELFV);
  uint32_t* pcG = (uint32_t*)(ws + OFF_PCG);
  uint32_t* enG = (uint32_t*)(ws + OFF_ENT);
  float* out    = (float*)d_out;

  k_prep<<<dim3(1076), dim3(256), 0, stream>>>(c1w, c2w, fcw, a0w, a1w, vw,
                                               a0b, a1b, vb, sw,
                                               w1t, w2b, fcb, wh, bh, swB);
  k_tok<<<dim3(B_TOT / GS), dim3(256), 0, stream>>>(obs, selfvB, enG, pcG);
  k_mlp<<<dim3(B_TOT / MB2), dim3(512), 0, stream>>>(enG, pcG, selfvB, w1t, w2b,
                                                     fcb, wh, swB, c1b, c2b,
                                                     fcbv, sb, bh, out);
}

// Round 18
// 54.046 us; speedup vs baseline: 1.0777x; 1.0777x over previous
//
#include <hip/hip_runtime.h>
#include <stdint.h>

typedef __bf16 bf16x8 __attribute__((ext_vector_type(8)));
typedef float  f32x4  __attribute__((ext_vector_type(4)));

#define B_TOT 16384
#define GS    4           // batches (waves) per tok block
#define MB2   32          // batches per k_mlp block
#define NPREP 1076        // prep blocks in the merged dispatch

// ws layout (byte offsets)
#define OFF_W1T   0u          // [550][128] bf16
#define OFF_W2B   141312u     // [128][1152] bf16 (w2b[oc][pos*128+ic])
#define OFF_FCB   436224u     // [256][128] bf16
#define OFF_WH    501760u     // [32][512] bf16 (head weights, N padded to 32)
#define OFF_BH    534528u     // [32] f32 head bias
#define OFF_SWB   534656u     // [256][32] bf16 self_w padded K 22->32
#define OFF_SELFV 551040u     // [16384][32] bf16 center-cell features
#define OFF_PCG   1599616u    // [16384][9] u32 bucket counts
#define OFF_ENT   2189440u    // [16384][9][12] u32 bucket entries (~7.1MB)

__device__ const float d_maxv[22] = {
  9.f,1.f,1.f,10.f,3.f,254.f,1.f,1.f,235.f,8.f,
  9.f,250.f,29.f,1.f,1.f,8.f,1.f,1.f,6.f,3.f,1.f,2.f };

static __device__ __forceinline__ short f2bf(float f){
  union { float f; uint32_t u; } c; c.f = f;
  uint32_t r = (c.u + 0x7FFFu + ((c.u >> 16) & 1u)) >> 16;  // RNE
  return (short)r;
}
static __device__ __forceinline__ float bf2f(short s){
  union { uint32_t u; float f; } c; c.u = ((uint32_t)(uint16_t)s) << 16;
  return c.f;
}
// packed RNE f32x2 -> bf16x2 (single HW instruction)
static __device__ __forceinline__ uint32_t cvtpk(float lo, float hi){
  uint32_t pk;
  asm("v_cvt_pk_bf16_f32 %0, %1, %2" : "=v"(pk) : "v"(lo), "v"(hi));
  return pk;
}
// XOR-swizzled short index for [row][k] LDS tiles (stride: shorts, mult of 64)
static __device__ __forceinline__ int swz(int row, int k, int stride){
  return row * stride + ((((k >> 3) ^ (row & 7)) << 3) | (k & 7));
}
// async global->LDS, 16B per lane; lds dest = wave-uniform base + lane*16
static __device__ __forceinline__ void gld16(const void* g, void* l){
  __builtin_amdgcn_global_load_lds(
      (const __attribute__((address_space(1))) void*)g,
      (__attribute__((address_space(3))) void*)l, 16, 0, 0);
}
static __device__ __forceinline__ void wavesync(){
  asm volatile("s_waitcnt lgkmcnt(0)" ::: "memory");
  __builtin_amdgcn_wave_barrier();
}

// ---- merged prep + tokenizer: blocks [0,NPREP) repack weights; the rest
//      parse/dedup/bucket tokens. The two halves touch disjoint data, so they
//      overlap inside one dispatch instead of serializing as two. ----
__global__ __launch_bounds__(256) void k_pt(
    const float* __restrict__ c1w, const float* __restrict__ c2w,
    const float* __restrict__ fcw, const float* __restrict__ a0w,
    const float* __restrict__ a1w, const float* __restrict__ vw,
    const float* __restrict__ a0b, const float* __restrict__ a1b,
    const float* __restrict__ vb,  const float* __restrict__ selfw,
    const int* __restrict__ obs,
    short* __restrict__ w1t, short* __restrict__ w2b, short* __restrict__ fcb,
    short* __restrict__ wh, float* __restrict__ bh, short* __restrict__ swB,
    short* __restrict__ selfvB, uint32_t* __restrict__ entG,
    uint32_t* __restrict__ pcntG)
{
  __shared__ uint32_t nzl[GS * 64];
  __shared__ uint32_t bkt[GS * 108];     // [4 batches][9 pos][12 slots]
  __shared__ uint32_t cnt[GS];
  __shared__ uint32_t pcnt[GS * 9];
  __shared__ float selfv[GS * 24];
  __shared__ float invS[22];

  if (blockIdx.x < NPREP) {
    // ---------------- prep branch ----------------
    int i = blockIdx.x * 256 + threadIdx.x;
    if (i < 70400) {                    // w1t[r*128+oc] = c1w[oc*550 + r]
      int r = i >> 7, oc = i & 127;
      w1t[i] = f2bf(c1w[oc * 550 + r]);
    }
    i -= 70400;
    if (i >= 0 && i < 147456) {         // w2b[oc*1152 + pos*128+ic]
      int oc = i / 1152, k = i - oc * 1152;
      int pos = k >> 7, ic = k & 127;
      w2b[i] = f2bf(c2w[oc * 1152 + ic * 9 + pos]);
    }
    i -= 147456;
    if (i >= 0 && i < 32768) fcb[i] = f2bf(fcw[i]);   // fc_w already [n][k]
    i -= 32768;
    if (i >= 0 && i < 16384) {          // wh[j*512+k], j in [0,32)
      int j = i >> 9, k = i & 511;
      float v = 0.f;
      if (j < 9) v = a0w[j * 512 + k];
      else if (j < 19) v = a1w[(j - 9) * 512 + k];
      else if (j == 19) v = vw[k];
      wh[i] = f2bf(v);
    }
    i -= 16384;
    if (i >= 0 && i < 32) {
      float v = 0.f;
      if (i < 9) v = a0b[i]; else if (i < 19) v = a1b[i - 9]; else if (i == 19) v = vb[0];
      bh[i] = v;
    }
    i -= 32;
    if (i >= 0 && i < 8192) {           // swB[o*32+l] = selfw[o*22+l], K-pad 0
      int o = i >> 5, l = i & 31;
      swB[i] = (l < 22) ? f2bf(selfw[o * 22 + l]) : (short)0;
    }
    return;
  }

  // ---------------- tokenizer branch ----------------
  const int tid = threadIdx.x, wid = tid >> 6, lane = tid & 63;
  const int b = (blockIdx.x - NPREP) * GS + wid;

  if (lane == 0) cnt[wid] = 0u;
  if (lane < 9)  pcnt[wid * 9 + lane] = 0u;
  if (lane < 24) selfv[wid * 24 + lane] = 0.f;
  for (int i = lane; i < 108; i += 64) bkt[wid * 108 + i] = 0u;  // determinism
  if (tid < 22) invS[tid] = 1.0f / (d_maxv[tid] + 1e-8f);
  __syncthreads();                       // invS

  // parse: wave-private batch, direct from global
  {
    const int* base = obs + (size_t)b * 600;
    #pragma unroll
    for (int k = 0; k < 4; ++k) {
      int m = lane + (k << 6);
      if (m < 200) {
        int c = base[m * 3], a = base[m * 3 + 1], v = base[m * 3 + 2];
        c = (c == 255) ? 0 : c;  a = (a == 255) ? 0 : a;  v = (v == 255) ? 0 : v;
        int x = (c >> 4) & 15, y = c & 15;
        if (x < 11 && y < 11 && a < 22) {
          uint32_t cell = (uint32_t)(a * 121 + x * 11 + y);
          uint32_t idx = atomicAdd(&cnt[wid], 1u);
          if (idx < 64u)
            nzl[wid * 64 + idx] = ((uint32_t)m << 20) | (cell << 8) | (uint32_t)v;
        }
      }
    }
  }
  wavesync();

  // dedup (last-write-wins = max pack per cell) + bucket expand + selfv
  {
    uint32_t n = cnt[wid]; if (n > 64u) n = 64u;
    for (uint32_t i = lane; i < n; i += 64) {
      uint32_t e = nzl[wid * 64 + i];
      uint32_t cell = (e >> 8) & 0xFFFu;
      uint32_t best = e;
      for (uint32_t j = 0; j < n; ++j) {
        uint32_t ej = nzl[wid * 64 + j];
        if ((((ej >> 8) & 0xFFFu) == cell) && ej > best) best = ej;
      }
      if (best == e && (e & 255u) != 0u) {
        uint32_t v8 = e & 255u;
        uint32_t l = cell / 121u, rem = cell - l * 121u;
        uint32_t x = rem / 11u, y = rem - x * 11u;
        if (rem == 60u)                            // x=5,y=5 center
          selfv[wid * 24 + l] = (float)v8 * invS[l];
        #pragma unroll
        for (int ox = 0; ox < 3; ++ox) {
          int kx = (int)x - 3 * ox; if (kx < 0 || kx > 4) continue;
          #pragma unroll
          for (int oy = 0; oy < 3; ++oy) {
            int ky = (int)y - 3 * oy; if (ky < 0 || ky > 4) continue;
            uint32_t r = l * 25u + (uint32_t)kx * 5u + (uint32_t)ky;
            uint32_t p = (uint32_t)(ox * 3 + oy);
            uint32_t s = atomicAdd(&pcnt[wid * 9 + p], 1u);
            if (s < 12u)
              bkt[wid * 108 + p * 12 + s] = (r << 13) | (l << 8) | v8;
          }
        }
      }
    }
  }
  wavesync();

  // selfvB [b][32] bf16 (K-padded)
  if (lane < 16) {
    int l0 = lane * 2;
    float v0 = (l0     < 22) ? selfv[wid * 24 + l0]     : 0.f;
    float v1 = (l0 + 1 < 22) ? selfv[wid * 24 + l0 + 1] : 0.f;
    *(uint32_t*)(selfvB + (size_t)b * 32 + l0) = cvtpk(v0, v1);
  }
  // write buckets + counts
  for (int i = lane; i < 108; i += 64) entG[(size_t)b * 108 + i] = bkt[wid * 108 + i];
  if (lane < 9) {
    uint32_t m = pcnt[wid * 9 + lane];
    pcntG[(size_t)b * 9 + lane] = (m > 12u) ? 12u : m;
  }
}

// -- fused conv1(per-position LDS A-tile) -> conv2 -> fc -> self -> heads --
// 32 batches/block, 512 threads, 56KB LDS -> 2 blocks/CU.
__global__ __launch_bounds__(512, 4) void k_mlp(
    const uint32_t* __restrict__ entG, const uint32_t* __restrict__ pcntG,
    const short* __restrict__ selfvB, const short* __restrict__ w1t,
    const short* __restrict__ w2b, const short* __restrict__ fcb,
    const short* __restrict__ wh,  const short* __restrict__ swB,
    const float* __restrict__ c1b, const float* __restrict__ c2b,
    const float* __restrict__ fcbias, const float* __restrict__ selfb,
    const float* __restrict__ bh, float* __restrict__ out)
{
  // shorts: Bbuf0 [0,8192) | Bbuf1 [8192,16384) | Atile [16384,20480)
  //         tokS u32 [20480,27392) | pcntS u32 [27392,27968) | invS [27968,28012)
  // post-conv2 aliases: h2s [0,4096) s128 | cfs [4096,12288) s256 |
  //                     sfl [12288,20480) s256 | hacc f32[2][1024] on [0,4096)
  __shared__ __align__(16) short smem[28032];
  uint32_t* tokS  = (uint32_t*)(smem + 20480);
  uint32_t* pcntS = (uint32_t*)(smem + 27392);
  float*    invL  = (float*)(smem + 27968);
  short*    Atile = smem + 16384;

  const int tid  = threadIdx.x, wid = tid >> 6, lane = tid & 63;
  const int l15 = lane & 15, kg = lane >> 4;
  const int wr = wid & 1, wc = wid >> 1;
  const int rowA = wr * 16 + l15;
  const size_t b0 = (size_t)blockIdx.x * MB2;
  const f32x4 z4 = {0.f, 0.f, 0.f, 0.f};

  // conv1 mapping: thread = (batch, ic-group of 8)
  const int cb1 = tid >> 4;           // batch 0..31
  const int icg = tid & 15;
  const int ic0 = icg * 8;

  // ---- stage tokS + pcntS + invS ----
  {
    const int4* src = (const int4*)(entG + b0 * 108);
    int4* dst = (int4*)tokS;
    for (int i = tid; i < 864; i += 512) dst[i] = src[i];
  }
  if (tid < 288) pcntS[tid] = pcntG[b0 * 9 + tid];
  if (tid < 22) invL[tid] = 1.0f / (d_maxv[tid] + 1e-8f);

  // conv1 bias in registers
  float bz[8];
  #pragma unroll
  for (int j = 0; j < 8; ++j) bz[j] = c1b[ic0 + j];

  // ---- B staging: 16 chunks/tile, wave w issues 2 ----
  const int sub = lane >> 3, pch = lane & 7;
  const int ocj0 = (wid * 2) * 8 + sub, ocj1 = (wid * 2 + 1) * 8 + sub;
  const short* gB0 = w2b + (size_t)ocj0 * 1152 + ((pch ^ (ocj0 & 7)) << 3);
  const short* gB1 = w2b + (size_t)ocj1 * 1152 + ((pch ^ (ocj1 & 7)) << 3);
  const int dB0 = (wid * 2) * 512, dB1 = (wid * 2 + 1) * 512;

  gld16(gB0, &smem[dB0]); gld16(gB1, &smem[dB1]);   // B(0) -> buf0
  __syncthreads();                                  // tokS visible (drains B(0) too)

  f32x4 acc[2] = {z4, z4};
  for (int t = 0; t < 18; ++t) {
    if ((t & 1) == 0) {
      // ---- produce A(p): conv1 for position p into Atile ----
      const int p = t >> 1;
      float a8[8];
      #pragma unroll
      for (int j = 0; j < 8; ++j) a8[j] = bz[j];
      const int n = (int)pcntS[cb1 * 9 + p];
      for (int i = 0; i < n; ++i) {
        uint32_t e = tokS[cb1 * 108 + p * 12 + i];
        int r = (int)(e >> 13);
        float vf = (float)(e & 255u) * invL[(e >> 8) & 31u];
        const uint32_t* wp = (const uint32_t*)(const void*)&w1t[r * 128 + ic0];
        uint32_t w0 = wp[0], w1 = wp[1], w2 = wp[2], w3 = wp[3];
        a8[0] += vf * bf2f((short)(w0 & 0xFFFFu));
        a8[1] += vf * bf2f((short)(w0 >> 16));
        a8[2] += vf * bf2f((short)(w1 & 0xFFFFu));
        a8[3] += vf * bf2f((short)(w1 >> 16));
        a8[4] += vf * bf2f((short)(w2 & 0xFFFFu));
        a8[5] += vf * bf2f((short)(w2 >> 16));
        a8[6] += vf * bf2f((short)(w3 & 0xFFFFu));
        a8[7] += vf * bf2f((short)(w3 >> 16));
      }
      uint32_t* ad = (uint32_t*)(void*)&Atile[swz(cb1, ic0, 128)];
      ad[0] = cvtpk(fmaxf(a8[0], 0.f), fmaxf(a8[1], 0.f));
      ad[1] = cvtpk(fmaxf(a8[2], 0.f), fmaxf(a8[3], 0.f));
      ad[2] = cvtpk(fmaxf(a8[4], 0.f), fmaxf(a8[5], 0.f));
      ad[3] = cvtpk(fmaxf(a8[6], 0.f), fmaxf(a8[7], 0.f));
    }
    const int cbB = (t & 1) * 8192;
    if (t < 17) {
      const int nbB = 8192 - cbB;
      const int ko = (t + 1) * 64;
      gld16(gB0 + ko, &smem[nbB + dB0]);
      gld16(gB1 + ko, &smem[nbB + dB1]);
      asm volatile("s_waitcnt vmcnt(2) lgkmcnt(0)" ::: "memory");
    } else {
      asm volatile("s_waitcnt vmcnt(0) lgkmcnt(0)" ::: "memory");
    }
    __builtin_amdgcn_sched_barrier(0);
    __builtin_amdgcn_s_barrier();       // B(t) staged + A(p) produced, all waves
    __builtin_amdgcn_sched_barrier(0);
    #pragma unroll
    for (int ks = 0; ks < 2; ++ks) {
      int kq = ks * 4 + kg;
      int icA = (t & 1) * 64 + kq * 8;
      bf16x8 a = *(const bf16x8*)(const void*)&Atile[swz(rowA, icA, 128)];
      #pragma unroll
      for (int nf = 0; nf < 2; ++nf) {
        int oc = wc * 32 + nf * 16 + l15;
        bf16x8 bv = *(const bf16x8*)(const void*)
                    &smem[cbB + oc * 64 + ((kq ^ (oc & 7)) << 3)];
        acc[nf] = __builtin_amdgcn_mfma_f32_16x16x32_bf16(a, bv, acc[nf], 0, 0, 0);
      }
    }
    __builtin_amdgcn_sched_barrier(0);
    __builtin_amdgcn_s_barrier();       // reads of buf + Atile done
  }
  // ---- conv2 epilogue: bias+relu -> h2s [0,4096), stride 128 ----
  #pragma unroll
  for (int nf = 0; nf < 2; ++nf) {
    int col = wc * 32 + nf * 16 + l15;
    float bias = c2b[col];
    #pragma unroll
    for (int rr = 0; rr < 4; ++rr) {      // C/D: col=lane&15, row=(lane>>4)*4+rr
      int row = wr * 16 + kg * 4 + rr;
      smem[swz(row, col, 128)] = f2bf(fmaxf(acc[nf][rr] + bias, 0.f));
    }
  }
  __syncthreads();

  // ---- fc GEMM: M=32 N=256 K=128; A from h2s, B from L2 -> cfs ----
  {
    f32x4 fca[4] = {z4, z4, z4, z4};
    #pragma unroll
    for (int kk = 0; kk < 4; ++kk) {
      int k = kk * 32 + kg * 8;
      bf16x8 a = *(const bf16x8*)(const void*)&smem[swz(rowA, k, 128)];
      #pragma unroll
      for (int nf = 0; nf < 4; ++nf) {
        int col = wc * 64 + nf * 16 + l15;
        bf16x8 bv = *(const bf16x8*)(const void*)(fcb + (size_t)col * 128 + k);
        fca[nf] = __builtin_amdgcn_mfma_f32_16x16x32_bf16(a, bv, fca[nf], 0, 0, 0);
      }
    }
    #pragma unroll
    for (int nf = 0; nf < 4; ++nf) {
      int col = wc * 64 + nf * 16 + l15;
      float bias = fcbias[col];
      #pragma unroll
      for (int rr = 0; rr < 4; ++rr) {
        int row = wr * 16 + kg * 4 + rr;
        smem[4096 + swz(row, col, 256)] = f2bf(fmaxf(fca[nf][rr] + bias, 0.f));
      }
    }
  }
  // ---- self encoder GEMM: M=32 N=256 K=32 -> sfl ----
  {
    f32x4 sa[4] = {z4, z4, z4, z4};
    bf16x8 a = *(const bf16x8*)(const void*)
               (selfvB + (b0 + (size_t)rowA) * 32 + kg * 8);
    #pragma unroll
    for (int nf = 0; nf < 4; ++nf) {
      int col = wc * 64 + nf * 16 + l15;
      bf16x8 bv = *(const bf16x8*)(const void*)(swB + (size_t)col * 32 + kg * 8);
      sa[nf] = __builtin_amdgcn_mfma_f32_16x16x32_bf16(a, bv, sa[nf], 0, 0, 0);
    }
    #pragma unroll
    for (int nf = 0; nf < 4; ++nf) {
      int col = wc * 64 + nf * 16 + l15;
      float bias = selfb[col];
      #pragma unroll
      for (int rr = 0; rr < 4; ++rr) {
        int row = wr * 16 + kg * 4 + rr;
        smem[12288 + swz(row, col, 256)] = f2bf(fmaxf(sa[nf][rr] + bias, 0.f));
      }
    }
  }
  __syncthreads();

  // ---- heads: M=32 N=32 K=512; waves = wr(2) x kh(2) x nh(2) ----
  {
    float* hacc = (float*)smem;           // [2][1024] f32, aliases h2s (dead)
    const int kh = (wid >> 1) & 1, nh = wid >> 2;
    const int ncol = nh * 16 + l15;
    f32x4 ha = z4;
    #pragma unroll
    for (int kk = 0; kk < 8; ++kk) {
      int kl = kk * 32 + kg * 8;
      bf16x8 a;
      if (kh == 0) a = *(const bf16x8*)(const void*)&smem[12288 + swz(rowA, kl, 256)];
      else         a = *(const bf16x8*)(const void*)&smem[4096  + swz(rowA, kl, 256)];
      bf16x8 bv = *(const bf16x8*)(const void*)(wh + (size_t)ncol * 512 + kh * 256 + kl);
      ha = __builtin_amdgcn_mfma_f32_16x16x32_bf16(a, bv, ha, 0, 0, 0);
    }
    #pragma unroll
    for (int rr = 0; rr < 4; ++rr) {
      int row = wr * 16 + kg * 4 + rr;
      hacc[kh * 1024 + row * 32 + ncol] = ha[rr];
    }
  }
  __syncthreads();

  // ---- reduce K-halves + bias + scatter ----
  {
    const float* hacc = (const float*)smem;
    #pragma unroll
    for (int q = 0; q < 2; ++q) {
      int i = q * 512 + tid;
      int row = i >> 5, colh = i & 31;
      float v = hacc[i] + hacc[1024 + i] + bh[colh];
      int gr = (int)b0 + row;
      if (colh < 9)        out[gr * 9 + colh] = v;                    // a0 [B][9]
      else if (colh < 19)  out[147456 + gr * 10 + (colh - 9)] = v;    // a1 [B][10]
      else if (colh == 19) out[311296 + gr] = v;                      // v  [B][1]
    }
  }
}

extern "C" void kernel_launch(void* const* d_in, const int* in_sizes, int n_in,
                              void* d_out, int out_size, void* d_ws, size_t ws_size,
                              hipStream_t stream)
{
  const int*   obs = (const int*)  d_in[0];
  const float* c1w = (const float*)d_in[1];
  const float* c1b = (const float*)d_in[2];
  const float* c2w = (const float*)d_in[3];
  const float* c2b = (const float*)d_in[4];
  const float* fcw = (const float*)d_in[5];
  const float* fcbv= (const float*)d_in[6];
  const float* sw  = (const float*)d_in[7];
  const float* sb  = (const float*)d_in[8];
  const float* a0w = (const float*)d_in[9];
  const float* a0b = (const float*)d_in[10];
  const float* a1w = (const float*)d_in[11];
  const float* a1b = (const float*)d_in[12];
  const float* vw  = (const float*)d_in[13];
  const float* vb  = (const float*)d_in[14];

  char* ws = (char*)d_ws;
  short* w1t    = (short*)(ws + OFF_W1T);
  short* w2b    = (short*)(ws + OFF_W2B);
  short* fcb    = (short*)(ws + OFF_FCB);
  short* wh     = (short*)(ws + OFF_WH);
  float* bh     = (float*)(ws + OFF_BH);
  short* swB    = (short*)(ws + OFF_SWB);
  short* selfvB = (short*)(ws + OFF_SELFV);
  uint32_t* pcG = (uint32_t*)(ws + OFF_PCG);
  uint32_t* enG = (uint32_t*)(ws + OFF_ENT);
  float* out    = (float*)d_out;

  k_pt<<<dim3(NPREP + B_TOT / GS), dim3(256), 0, stream>>>(
      c1w, c2w, fcw, a0w, a1w, vw, a0b, a1b, vb, sw, obs,
      w1t, w2b, fcb, wh, bh, swB, selfvB, enG, pcG);
  k_mlp<<<dim3(B_TOT / MB2), dim3(512), 0, stream>>>(enG, pcG, selfvB, w1t, w2b,
                                                     fcb, wh, swB, c1b, c2b,
                                                     fcbv, sb, bh, out);
}